// Round 4
// baseline (1058.119 us; speedup 1.0000x reference)
//
#include <hip/hip_runtime.h>
#include <math.h>

#define DIM  2048
#define NH   1024
#define NBLK 1024

// ---- workspace layout (float offsets) ----
#define OFF_PART1 0u            // [32][8192][16] = 4194304
#define OFF_NUM   4194304u      // [8192][16]
#define OFF_COMB  4325376u      // [8192][16]
#define OFF_CSUM  4456448u      // [1024][16]
#define OFF_MUSUM 4472832u      // [1024][16]
#define OFF_ENT   4489216u      // [1024]
#define OFF_INVS  4490240u      // [16]
#define OFF_PART6 4490256u      // [128][16][2048] = 4194304
#define OFF_SRAW  8684560u      // [16][2048]
#define OFF_RAWH  8717328u      // [4][16][1024] = 65536
#define OFF_SLOT  8782864u      // [16][2048]
#define OFF_CNT   8815632u      // 8 uints (barrier counters)

// ---- d_out layout (float offsets) ----
#define O_OUT   0u
#define O_LOSS  16777216u
#define O_GATE  16777217u
#define O_TOPI  16908289u
#define O_TOPW  16924673u
#define O_MU    16941057u
#define O_ENTR  16941073u
#define O_DISP  16941074u

__device__ __forceinline__ float wave_sum(float v){
  #pragma unroll
  for (int o=1;o<64;o<<=1) v += __shfl_xor(v,o,64);
  return v;
}
__device__ __forceinline__ float gelu(float x){
  return 0.5f*x*(1.f+erff(x*0.70710678118654752f));
}

// device-scope grid barrier: all NBLK blocks are co-resident by construction
// (1024 blocks = 4/CU; VGPR<=128 via launch_bounds, LDS 12KB, 16 waves/CU).
__device__ __forceinline__ void gbar(unsigned* cnt){
  __syncthreads();
  if (threadIdx.x==0){
    __hip_atomic_fetch_add(cnt, 1u, __ATOMIC_RELEASE, __HIP_MEMORY_SCOPE_AGENT);
    while (__hip_atomic_load(cnt, __ATOMIC_ACQUIRE, __HIP_MEMORY_SCOPE_AGENT) < NBLK)
      __builtin_amdgcn_s_sleep(2);
  }
  __syncthreads();
}

__global__ void kinit(unsigned* cnt){
  if (threadIdx.x < 8) cnt[threadIdx.x] = 0u;
}

__global__ __launch_bounds__(256,4) void fused(
    const float* __restrict__ x,  const float* __restrict__ Wd,
    const float* __restrict__ W1, const float* __restrict__ b1,
    const float* __restrict__ W2, const float* __restrict__ b2,
    float* __restrict__ ws, float* __restrict__ out, unsigned* __restrict__ cnt){
  const int gid = blockIdx.x;
  const int tid = threadIdx.x;
  __shared__ float4 smem4[768];                 // 12 KB, reused per phase
  float* smem = (float*)smem4;

  float* part1 = ws + OFF_PART1;
  float* num   = ws + OFF_NUM;
  float* comb  = ws + OFF_COMB;
  float* csum  = ws + OFF_CSUM;
  float* musum = ws + OFF_MUSUM;
  float* entp  = ws + OFF_ENT;
  float* invs  = ws + OFF_INVS;
  float* part6 = ws + OFF_PART6;
  float* sraw  = ws + OFF_SRAW;
  float* rawh4 = ws + OFF_RAWH;
  float* slot  = ws + OFF_SLOT;

  // ---------------- P1: logits partials. 1024 = 32tb(256tok) x 32kc(64k)
  {
    const int tb = gid>>5, kc = gid&31;
    const int t  = tb*256 + tid;
    const float4* xr = (const float4*)(x + (size_t)t*DIM + kc*64);
    float acc[16];
    #pragma unroll
    for (int e=0;e<16;e++) acc[e]=0.f;
    #pragma unroll 4
    for (int k4=0;k4<16;k4++){
      float4 xv = xr[k4];
      #pragma unroll
      for (int e=0;e<16;e++){
        float4 w = *(const float4*)(Wd + e*DIM + kc*64 + k4*4);
        acc[e] += xv.x*w.x + xv.y*w.y + xv.z*w.z + xv.w*w.w;
      }
    }
    float4* po = (float4*)(part1 + ((size_t)kc*8192 + t)*16);
    po[0]=make_float4(acc[0],acc[1],acc[2],acc[3]);
    po[1]=make_float4(acc[4],acc[5],acc[6],acc[7]);
    po[2]=make_float4(acc[8],acc[9],acc[10],acc[11]);
    po[3]=make_float4(acc[12],acc[13],acc[14],acc[15]);
  }
  gbar(cnt+0);

  // ---------------- P2: logits reduce, num=exp, row softmax, partials. 8 tok/blk
  {
    const int t0 = gid*8;
    const int h = tid&1, pr = tid>>1, tt = pr>>4, e = pr&15;
    float v = 0.f;
    #pragma unroll
    for (int j=0;j<16;j++)
      v += part1[(size_t)(h*16+j)*131072 + (size_t)(t0+tt)*16 + e];
    v += __shfl_xor(v,1,64);                    // combine kc halves
    // LDS: sl[0..128) logits, sn[128..256) exp, sc[256..384) combine, se[384..392)
    if (h==0){
      float n = expf(v);                        // |logit| < ~6, safe without shift
      num[(size_t)(t0+tt)*16 + e] = n;
      smem[tt*16+e] = v;
      smem[128 + tt*16+e] = n;
    }
    __syncthreads();
    if (tid<16){
      float s=0.f;
      #pragma unroll
      for (int k=0;k<8;k++) s += smem[128 + k*16 + tid];
      csum[gid*16+tid] = s;
    }
    if (tid<8){
      const int gt = t0 + tid;
      float l[16], c[16];
      #pragma unroll
      for (int e2=0;e2<16;e2++) l[e2] = smem[tid*16+e2];
      float m = l[0];
      #pragma unroll
      for (int e2=1;e2<16;e2++) m = fmaxf(m,l[e2]);
      float s=0.f;
      #pragma unroll
      for (int e2=0;e2<16;e2++){ c[e2]=expf(l[e2]-m); s+=c[e2]; }
      float inv = 1.f/s;
      #pragma unroll
      for (int e2=0;e2<16;e2++) c[e2]*=inv;
      float4* co = (float4*)(comb + (size_t)gt*16);
      co[0]=make_float4(c[0],c[1],c[2],c[3]);   co[1]=make_float4(c[4],c[5],c[6],c[7]);
      co[2]=make_float4(c[8],c[9],c[10],c[11]); co[3]=make_float4(c[12],c[13],c[14],c[15]);
      float* go = out + O_GATE + (size_t)gt*16; // unaligned region -> scalar
      #pragma unroll
      for (int e2=0;e2<16;e2++) go[e2]=c[e2];
      float v0=-1.f,v1=-1.f; int i0=0,i1=0;
      #pragma unroll
      for (int e2=0;e2<16;e2++){
        float ce=c[e2];
        if (ce>v0){ v1=v0;i1=i0; v0=ce;i0=e2; }
        else if (ce>v1){ v1=ce;i1=e2; }
      }
      float dn = fmaxf(v0+v1,1e-8f);
      out[O_TOPI + (size_t)gt*2+0]=(float)i0; out[O_TOPI + (size_t)gt*2+1]=(float)i1;
      out[O_TOPW + (size_t)gt*2+0]=v0/dn;     out[O_TOPW + (size_t)gt*2+1]=v1/dn;
      float ent=0.f;
      #pragma unroll
      for (int e2=0;e2<16;e2++) ent -= c[e2]*logf(c[e2]+1e-8f);
      #pragma unroll
      for (int e2=0;e2<16;e2++) smem[256 + tid*16+e2] = c[e2];
      smem[384+tid] = ent;
    }
    __syncthreads();
    if (tid<16){
      float s=0.f;
      #pragma unroll
      for (int k=0;k<8;k++) s += smem[256 + k*16 + tid];
      musum[gid*16+tid] = s;
    }
    if (tid==16){
      float s=0.f;
      #pragma unroll
      for (int k=0;k<8;k++) s += smem[384+k];
      entp[gid] = s;
    }
  }
  gbar(cnt+1);

  // ---------------- P4: slot_in partials + dispatch + (block0) finalize.
  // 1024 = 128tc(64tok) x 8dc(256d)
  {
    const int tc = gid>>3, dc = gid&7;
    const int t0 = tc*64, d = dc*256 + tid;
    // stage num[t0..t0+64)[16] -> smem[0..1024)
    smem4[tid] = ((const float4*)(num + (size_t)t0*16))[tid];
    __syncthreads();
    const float* sN = smem;
    float acc[16];
    #pragma unroll
    for (int e=0;e<16;e++) acc[e]=0.f;
    #pragma unroll 4
    for (int t=0;t<64;t++){
      float xv = x[(size_t)(t0+t)*DIM + d];
      #pragma unroll
      for (int e=0;e<16;e++) acc[e] = fmaf(sN[t*16+e], xv, acc[e]);
    }
    #pragma unroll
    for (int e=0;e<16;e++)
      part6[((size_t)tc*16+e)*DIM + d] = acc[e];

    if (dc==0){
      // inv_s from csum partials (L2-hot, 128 blocks do this)
      { int g = tid>>4, e = tid&15;
        float s=0.f;
        for (int k=0;k<64;k++) s += csum[(size_t)(g*64+k)*16 + e];
        smem[1024 + g*16 + e] = s; }
      __syncthreads();
      if (tid<16){
        float s=0.f;
        #pragma unroll
        for (int g=0;g<16;g++) s += smem[1024 + g*16 + tid];
        smem[1280+tid] = 1.f/s;
      }
      __syncthreads();
      #pragma unroll
      for (int r=0;r<4;r++){
        int j = r*256 + tid;
        out[O_DISP + (size_t)t0*16 + j] = sN[j]*smem[1280 + (j&15)];
      }
      if (gid==0){
        if (tid<16) invs[tid] = smem[1280+tid];
        __syncthreads();                         // sN dead from here, reuse smem
        { int g = tid>>4, e = tid&15;
          float s=0.f;
          for (int k=0;k<64;k++) s += musum[(size_t)(g*64+k)*16 + e];
          smem[g*16+e] = s; }
        { float s=0.f;
          #pragma unroll
          for (int k=0;k<4;k++) s += entp[tid*4+k];
          smem[272+tid] = s; }
        { int sr = tid>>4, ch = tid&15;          // p: Wd chunk sums
          const float* base = Wd + (size_t)sr*DIM + ch*128;
          float q=0.f;
          for (int i=0;i<128;i+=4){ float4 vv=*(const float4*)(base+i); q+=vv.x+vv.y+vv.z+vv.w; }
          smem[528 + sr*16 + ch] = q; }
        __syncthreads();
        if (tid<16){
          float mu=0.f;
          #pragma unroll
          for (int g=0;g<16;g++) mu += smem[g*16+tid];
          mu /= 8192.f;
          out[O_MU + tid] = mu;
          smem[256+tid] = mu;
        }
        if (tid>=64 && tid<128){
          int q = tid-64;
          float s = smem[272+q]+smem[272+q+64]+smem[272+q+128]+smem[272+q+192];
          s = wave_sum(s);
          if (q==0) out[O_ENTR] = s/8192.f;
        }
        if (tid>=32 && tid<48){
          float q=0.f;
          #pragma unroll
          for (int sr=0;sr<16;sr++) q += smem[528 + sr*16 + (tid-32)];
          smem[784 + (tid-32)] = q/2048.f;
        }
        __syncthreads();
        if (tid==0){
          float qm=-INFINITY;
          for (int e=0;e<16;e++) qm = fmaxf(qm, smem[784+e]);
          float qs=0.f, qe[16];
          for (int e=0;e<16;e++){ qe[e]=expf(smem[784+e]-qm); qs+=qe[e]; }
          float loss=0.f;
          for (int e=0;e<16;e++) loss += smem[256+e]*(qe[e]/qs);
          out[O_LOSS] = 16.f*loss;
        }
      }
    }
  }
  gbar(cnt+2);

  // ---------------- P5: sraw[o] = inv_s[e] * sum_tc part6. 1024 x 32 outputs
  {
    const int o0 = gid*32;
    const int o = o0 + (tid&31), sl5 = tid>>5;   // 8 slices x 16 tc
    float s=0.f;
    #pragma unroll
    for (int k=0;k<16;k++) s += part6[(size_t)(sl5*16+k)*32768 + o];
    smem[tid] = s;
    __syncthreads();
    if (tid<32){
      float t=0.f;
      #pragma unroll
      for (int k=0;k<8;k++) t += smem[k*32+tid];
      int oo = o0 + tid;
      sraw[oo] = t * invs[oo>>11];
    }
  }
  gbar(cnt+3);

  // ---------------- P6: rawh4[dp][e][h] partials. 1024 = 16e x 16hc(64h) x 4dp(512d)
  {
    const int e  = gid>>6;
    const int hc = (gid>>2)&15, dp = gid&3;
    const int hbase = hc*64;
    if (tid<128)
      smem4[tid] = ((const float4*)(sraw + (size_t)e*DIM + dp*512))[tid]; // sr[512]
    __syncthreads();
    const int hq = tid&15, ds = tid>>4;          // 16 h-float4 x 16 d-slices(32)
    float4 acc = make_float4(0,0,0,0);
    const float* wp = W1 + ((size_t)e*DIM + dp*512)*NH + hbase + hq*4;
    #pragma unroll 8
    for (int i=0;i<32;i++){
      const int dd = ds*32 + i;
      float4 w = *(const float4*)(wp + (size_t)dd*NH);
      float s = smem[dd];
      acc.x=fmaf(s,w.x,acc.x); acc.y=fmaf(s,w.y,acc.y);
      acc.z=fmaf(s,w.z,acc.z); acc.w=fmaf(s,w.w,acc.w);
    }
    __syncthreads();
    smem4[128+tid] = acc;
    __syncthreads();
    if (tid<16){
      float4 a = make_float4(0,0,0,0);
      #pragma unroll
      for (int k=0;k<16;k++){
        float4 v = smem4[128 + k*16 + tid];
        a.x+=v.x; a.y+=v.y; a.z+=v.z; a.w+=v.w;
      }
      *(float4*)(rawh4 + ((size_t)dp*16+e)*NH + hbase + tid*4) = a;
    }
  }
  gbar(cnt+4);

  // ---------------- P7: slot_out. 1024 = 16e x 64dc(32d); h staged w/ gelu
  {
    const int e  = gid>>6;
    const int dc = gid&63;
    const int dbase = dc*32;
    { const float4* r4 = (const float4*)rawh4;
      float4 v0 = r4[(size_t)(0*16+e)*256 + tid];
      float4 v1 = r4[(size_t)(1*16+e)*256 + tid];
      float4 v2 = r4[(size_t)(2*16+e)*256 + tid];
      float4 v3 = r4[(size_t)(3*16+e)*256 + tid];
      float4 bb = ((const float4*)(b1 + (size_t)e*NH))[tid];
      float4 pre = make_float4(v0.x+v1.x+v2.x+v3.x+bb.x, v0.y+v1.y+v2.y+v3.y+bb.y,
                               v0.z+v1.z+v2.z+v3.z+bb.z, v0.w+v1.w+v2.w+v3.w+bb.w);
      smem4[tid] = make_float4(gelu(pre.x),gelu(pre.y),gelu(pre.z),gelu(pre.w)); }
    __syncthreads();
    const float* hh = smem;                      // [1024]
    const int dq = tid&7, hs = tid>>3;           // 8 d-float4 x 32 h-slices(32)
    float4 acc = make_float4(0,0,0,0);
    const float* wp = W2 + (size_t)e*NH*DIM + dbase + dq*4;
    #pragma unroll 8
    for (int i=0;i<32;i++){
      const int hidx = hs*32 + i;
      float4 w = *(const float4*)(wp + (size_t)hidx*DIM);
      float s = hh[hidx];
      acc.x=fmaf(s,w.x,acc.x); acc.y=fmaf(s,w.y,acc.y);
      acc.z=fmaf(s,w.z,acc.z); acc.w=fmaf(s,w.w,acc.w);
    }
    __syncthreads();
    smem4[256+tid] = acc;
    __syncthreads();
    if (tid<8){
      float4 a = make_float4(0,0,0,0);
      #pragma unroll
      for (int k=0;k<32;k++){
        float4 v = smem4[256 + k*8 + tid];
        a.x+=v.x; a.y+=v.y; a.z+=v.z; a.w+=v.w;
      }
      float4 bb = *(const float4*)(b2 + (size_t)e*DIM + dbase + tid*4);
      a.x+=bb.x; a.y+=bb.y; a.z+=bb.z; a.w+=bb.w;
      *(float4*)(slot + (size_t)e*DIM + dbase + tid*4) = a;
    }
  }
  gbar(cnt+5);

  // ---------------- P8: out = combine @ slot_out. 1024 x 8 tokens
  {
    const int t0 = gid*8;
    if (tid<32) smem4[tid] = ((const float4*)(comb + (size_t)t0*16))[tid];
    __syncthreads();
    const float* sc = smem;                      // [8][16]
    #pragma unroll
    for (int dc=0;dc<2;dc++){
      const int d = dc*1024 + tid*4;
      float4 sv[16];
      #pragma unroll
      for (int e=0;e<16;e++) sv[e] = *(const float4*)(slot + (size_t)e*DIM + d);
      #pragma unroll
      for (int t=0;t<8;t++){
        const float* cr = sc + t*16;
        float4 a = make_float4(0,0,0,0);
        #pragma unroll
        for (int e=0;e<16;e++){
          float c = cr[e];
          a.x=fmaf(c,sv[e].x,a.x); a.y=fmaf(c,sv[e].y,a.y);
          a.z=fmaf(c,sv[e].z,a.z); a.w=fmaf(c,sv[e].w,a.w);
        }
        *(float4*)(out + (size_t)(t0+t)*DIM + d) = a;
      }
    }
  }
}

extern "C" void kernel_launch(void* const* d_in, const int* in_sizes, int n_in,
                              void* d_out, int out_size, void* d_ws, size_t ws_size,
                              hipStream_t stream) {
  const float* x  = (const float*)d_in[0];
  const float* Wd = (const float*)d_in[1];
  const float* W1 = (const float*)d_in[2];
  const float* b1 = (const float*)d_in[3];
  const float* W2 = (const float*)d_in[4];
  const float* b2 = (const float*)d_in[5];
  float* out = (float*)d_out;
  float* ws  = (float*)d_ws;
  unsigned* cnt = (unsigned*)(ws + OFF_CNT);

  kinit<<<1, 64, 0, stream>>>(cnt);
  fused<<<NBLK, 256, 0, stream>>>(x, Wd, W1, b1, W2, b2, ws, out, cnt);
}

// Round 5
// 889.414 us; speedup vs baseline: 1.1897x; 1.1897x over previous
//
#include <hip/hip_runtime.h>
#include <math.h>

#define TTOK 8192
#define DIM  2048
#define NH   1024
#define REP_BIG 8

// ---- workspace layout (float offsets) ----
#define OFF_PART1   0u           // [16][8192][16] = 2097152
#define OFF_NUM     2097152u     // [8192][16]
#define OFF_COMBINE 2228224u     // [8192][16]
#define OFF_CSUM    2359296u     // [128][16]
#define OFF_MUSUM   2361344u     // [128][16]
#define OFF_ENT     2363392u     // [128]
#define OFF_PART6   2363520u     // [256][16][2048] = 8388608
#define OFF_SRAW    10752128u    // [16][2048]
#define OFF_HBUF    10784896u    // [16][1024]
#define OFF_SLOT    10801280u    // [16][2048]

// ---- d_out layout (float offsets) ----
#define O_OUT   0u
#define O_LOSS  16777216u
#define O_GATE  16777217u
#define O_TOPI  16908289u
#define O_TOPW  16924673u
#define O_MU    16941057u
#define O_ENTR  16941073u
#define O_DISP  16941074u

__device__ __forceinline__ float wave_sum(float v){
  #pragma unroll
  for (int o=1;o<64;o<<=1) v += __shfl_xor(v,o,64);
  return v;
}

// KA: logits partials. grid 512 = 32 token-blocks x 16 k-chunks(128). REP x8 diagnostic.
__global__ __launch_bounds__(256) void ka_logits(const float* __restrict__ x,
                                                 const float* __restrict__ Wd,
                                                 float* __restrict__ part1){
  const int tb = blockIdx.x >> 4;
  const int kc = blockIdx.x & 15;
  const int t  = tb*256 + threadIdx.x;
  for (int rep=0; rep<REP_BIG; rep++){
    const float4* __restrict__ xr = (const float4*)(x + (size_t)t*DIM + kc*128);
    float acc[16];
    #pragma unroll
    for (int e=0;e<16;e++) acc[e]=0.f;
    #pragma unroll 4
    for (int k4=0;k4<32;k4++){
      float4 xv = xr[k4];
      #pragma unroll
      for (int e=0;e<16;e++){
        float4 w = *(const float4*)(Wd + e*DIM + kc*128 + k4*4);
        acc[e] += xv.x*w.x + xv.y*w.y + xv.z*w.z + xv.w*w.w;
      }
    }
    float4* po = (float4*)(part1 + ((size_t)kc*TTOK + t)*16);
    po[0] = make_float4(acc[0],acc[1],acc[2],acc[3]);
    po[1] = make_float4(acc[4],acc[5],acc[6],acc[7]);
    po[2] = make_float4(acc[8],acc[9],acc[10],acc[11]);
    po[3] = make_float4(acc[12],acc[13],acc[14],acc[15]);
  }
}

// KB: reduce part1 -> logits; num=exp; csum partials; row softmax outputs. grid 128
__global__ __launch_bounds__(256) void kb_router(const float* __restrict__ part1,
    float* __restrict__ num, float* __restrict__ csum_part,
    float* __restrict__ combine, float* __restrict__ gate_out,
    float* __restrict__ topi_out, float* __restrict__ topw_out,
    float* __restrict__ musum_part, float* __restrict__ ent_part){
  const int tid = threadIdx.x;
  const int i = blockIdx.x*256 + tid;
  const float4* p1 = (const float4*)part1;
  float4 s = make_float4(0,0,0,0);
  #pragma unroll
  for (int kc=0;kc<16;kc++){
    float4 v = p1[(size_t)kc*32768 + i];
    s.x+=v.x; s.y+=v.y; s.z+=v.z; s.w+=v.w;
  }
  float4 n4 = make_float4(expf(s.x),expf(s.y),expf(s.z),expf(s.w));
  ((float4*)num)[i] = n4;
  __shared__ float Lg[64][20];
  const int tl = tid>>2, q = tid&3;
  *(float4*)(&Lg[tl][q*4]) = s;
  float4 n = n4;
  #pragma unroll
  for (int o=4;o<64;o<<=1){
    n.x += __shfl_xor(n.x,o,64); n.y += __shfl_xor(n.y,o,64);
    n.z += __shfl_xor(n.z,o,64); n.w += __shfl_xor(n.w,o,64);
  }
  __shared__ float4 red[4][4];
  const int w = tid>>6, lane = tid&63;
  if (lane<4) red[w][lane] = n;
  __syncthreads();
  if (tid<4){
    float4 a=red[0][tid],b=red[1][tid],c=red[2][tid],d=red[3][tid];
    *(float4*)(csum_part + blockIdx.x*16 + tid*4) =
      make_float4(a.x+b.x+c.x+d.x, a.y+b.y+c.y+d.y, a.z+b.z+c.z+d.z, a.w+b.w+c.w+d.w);
  }
  if (tid < 64){
    const int gt = blockIdx.x*64 + tid;
    float l[16];
    #pragma unroll
    for (int e=0;e<16;e++) l[e] = Lg[tid][e];
    float m = l[0];
    #pragma unroll
    for (int e=1;e<16;e++) m = fmaxf(m,l[e]);
    float c[16]; float sm=0.f;
    #pragma unroll
    for (int e=0;e<16;e++){ c[e]=expf(l[e]-m); sm+=c[e]; }
    float inv = 1.f/sm;
    #pragma unroll
    for (int e=0;e<16;e++) c[e]*=inv;
    float4* co = (float4*)(combine + (size_t)gt*16);
    co[0]=make_float4(c[0],c[1],c[2],c[3]);   co[1]=make_float4(c[4],c[5],c[6],c[7]);
    co[2]=make_float4(c[8],c[9],c[10],c[11]); co[3]=make_float4(c[12],c[13],c[14],c[15]);
    float* go = gate_out + (size_t)gt*16;
    #pragma unroll
    for (int e=0;e<16;e++) go[e]=c[e];
    float v0=-1.f, v1=-1.f; int i0=0, i1=0;
    #pragma unroll
    for (int e=0;e<16;e++){
      float ce=c[e];
      if (ce>v0){ v1=v0; i1=i0; v0=ce; i0=e; }
      else if (ce>v1){ v1=ce; i1=e; }
    }
    float dn = fmaxf(v0+v1, 1e-8f);
    topi_out[(size_t)gt*2+0]=(float)i0; topi_out[(size_t)gt*2+1]=(float)i1;
    topw_out[(size_t)gt*2+0]=v0/dn;     topw_out[(size_t)gt*2+1]=v1/dn;
    float ent=0.f;
    #pragma unroll
    for (int e=0;e<16;e++) ent -= c[e]*logf(c[e]+1e-8f);
    #pragma unroll
    for (int e=0;e<16;e++){
      float v = wave_sum(c[e]);
      if (tid==0) musum_part[blockIdx.x*16+e] = v;
    }
    float ve = wave_sum(ent);
    if (tid==0) ent_part[blockIdx.x] = ve;
  }
}

// KD: slot_in partials + dispatch + block0 finalize. grid 512. REP x8 diagnostic.
__global__ __launch_bounds__(256) void kd_slotin(const float* __restrict__ x,
    const float* __restrict__ num, const float* __restrict__ csum_part,
    const float* __restrict__ musum_part, const float* __restrict__ ent_part,
    const float* __restrict__ Wd,
    float* __restrict__ part6, float* __restrict__ disp_out,
    float* __restrict__ loss_out, float* __restrict__ mu_out, float* __restrict__ ent_out){
  const int tc = blockIdx.x >> 1;
  const int dc = blockIdx.x & 1;
  const int tid = threadIdx.x;
  const int d  = dc*1024 + tid*4;
  const int t0 = tc*32;
  __shared__ float4 sN[128];
  for (int rep=0; rep<REP_BIG; rep++){
    if (tid < 128) sN[tid] = ((const float4*)num)[t0*4 + tid];
    __syncthreads();
    float4 acc[16];
    #pragma unroll
    for (int e=0;e<16;e++) acc[e]=make_float4(0,0,0,0);
    #pragma unroll 2
    for (int t=0;t<32;t++){
      const float4 xv = *(const float4*)(x + (size_t)(t0+t)*DIM + d);
      #pragma unroll
      for (int qq=0;qq<4;qq++){
        float4 nq = sN[t*4+qq];
        acc[qq*4+0].x=fmaf(nq.x,xv.x,acc[qq*4+0].x); acc[qq*4+0].y=fmaf(nq.x,xv.y,acc[qq*4+0].y);
        acc[qq*4+0].z=fmaf(nq.x,xv.z,acc[qq*4+0].z); acc[qq*4+0].w=fmaf(nq.x,xv.w,acc[qq*4+0].w);
        acc[qq*4+1].x=fmaf(nq.y,xv.x,acc[qq*4+1].x); acc[qq*4+1].y=fmaf(nq.y,xv.y,acc[qq*4+1].y);
        acc[qq*4+1].z=fmaf(nq.y,xv.z,acc[qq*4+1].z); acc[qq*4+1].w=fmaf(nq.y,xv.w,acc[qq*4+1].w);
        acc[qq*4+2].x=fmaf(nq.z,xv.x,acc[qq*4+2].x); acc[qq*4+2].y=fmaf(nq.z,xv.y,acc[qq*4+2].y);
        acc[qq*4+2].z=fmaf(nq.z,xv.z,acc[qq*4+2].z); acc[qq*4+2].w=fmaf(nq.z,xv.w,acc[qq*4+2].w);
        acc[qq*4+3].x=fmaf(nq.w,xv.x,acc[qq*4+3].x); acc[qq*4+3].y=fmaf(nq.w,xv.y,acc[qq*4+3].y);
        acc[qq*4+3].z=fmaf(nq.w,xv.z,acc[qq*4+3].z); acc[qq*4+3].w=fmaf(nq.w,xv.w,acc[qq*4+3].w);
      }
    }
    #pragma unroll
    for (int e=0;e<16;e++)
      *(float4*)(part6 + ((size_t)tc*16+e)*DIM + d) = acc[e];

    if (dc==0){
      __shared__ float sIv[16][16];
      __shared__ float sInv[16];
      { int g = tid>>4, e = tid&15;
        float v=0.f;
        #pragma unroll
        for (int k=0;k<8;k++) v += csum_part[(g*8+k)*16 + e];
        sIv[g][e]=v; }
      __syncthreads();
      if (tid<16){
        float v=0.f;
        #pragma unroll
        for (int g2=0;g2<16;g2++) v+=sIv[g2][tid];
        sInv[tid]=1.f/v;
      }
      __syncthreads();
      const float* sNf = (const float*)sN;
      const int j = tid*2;
      float2 dv = make_float2(sNf[j]*sInv[j&15], sNf[j+1]*sInv[(j+1)&15]);
      *(float2*)(disp_out + (size_t)t0*16 + j) = dv;

      if (tc==0){
        __shared__ float sq[16][16];
        __shared__ float smu[16];
        __shared__ float sqv[16];
        __shared__ float sqe[16];
        {
          int s = tid>>4, ch = tid&15;
          const float* base = Wd + (size_t)s*DIM + ch*128;
          float qv=0.f;
          for (int ii=0;ii<128;ii+=4){ float4 v=*(const float4*)(base+ii); qv+=v.x+v.y+v.z+v.w; }
          sq[s][ch]=qv;
        }
        if (tid<16){
          float mu=0.f;
          for (int b=0;b<128;b++) mu += musum_part[b*16+tid];
          mu/=8192.f;
          mu_out[tid]=mu; smu[tid]=mu;
        }
        if (tid==32){ float es=0.f; for(int b=0;b<128;b++) es+=ent_part[b]; ent_out[0]=es/8192.f; }
        __syncthreads();
        if (tid<16){ float qv=0.f; for(int s=0;s<16;s++) qv+=sq[s][tid]; sqv[tid]=qv/2048.f; }
        __syncthreads();
        if (tid<16){
          float qm=-INFINITY;
          for (int e=0;e<16;e++) qm=fmaxf(qm,sqv[e]);
          sqe[tid]=expf(sqv[tid]-qm);
        }
        __syncthreads();
        if (tid==0){
          float qs=0.f; for(int e=0;e<16;e++) qs+=sqe[e];
          float loss=0.f; for(int e=0;e<16;e++) loss+=smu[e]*(sqe[e]/qs);
          loss_out[0]=16.f*loss;
        }
      }
    }
    __syncthreads();
  }
}

// KE: sraw_raw[i] = sum_tc part6[tc][i]. grid 256 x 256
__global__ __launch_bounds__(256) void ke_sraw(const float* __restrict__ part6,
    float* __restrict__ sraw){
  const int tid = threadIdx.x;
  const int half = tid>>7, il = tid&127;
  const int i = blockIdx.x*128 + il;
  float s=0.f;
  #pragma unroll 8
  for (int tc=half*128; tc<half*128+128; tc++) s += part6[(size_t)tc*32768 + i];
  __shared__ float s2[256];
  s2[tid]=s;
  __syncthreads();
  if (tid<128){
    int ii = blockIdx.x*128 + tid;
    sraw[ii] = s2[tid]+s2[tid+128];
  }
}

// KF: h-GEMV. grid 512 = 16e x 32hc. REP x8 diagnostic.
__global__ __launch_bounds__(256) void kf_h(const float* __restrict__ sraw,
    const float* __restrict__ W1, const float* __restrict__ b1,
    const float* __restrict__ csum_part, float* __restrict__ hbuf){
  const int e  = blockIdx.x >> 5;
  const int hc = blockIdx.x & 31;
  const int hbase = hc*32;
  const int tid = threadIdx.x;
  __shared__ float sr[2048];
  __shared__ float sacc[256];
  __shared__ float sIpart[2];
  for (int rep=0; rep<REP_BIG; rep++){
    { const float4* s4 = (const float4*)(sraw + (size_t)e*DIM);
      float4 a = s4[tid*2], b = s4[tid*2+1];
      *(float4*)(&sr[tid*8]) = a; *(float4*)(&sr[tid*8+4]) = b; }
    if (tid < 128){
      float v = csum_part[tid*16 + e];
      #pragma unroll
      for (int o=1;o<64;o<<=1) v += __shfl_xor(v,o,64);
      if ((tid&63)==0) sIpart[tid>>6] = v;
    }
    __syncthreads();
    const int hl = tid&31, ds = tid>>5;
    float acc = 0.f;
    const float* wp = W1 + (size_t)e*DIM*NH + hbase + hl;
    #pragma unroll 16
    for (int d2=0; d2<256; d2++){
      const int dd = d2*8 + ds;
      acc = fmaf(sr[dd], wp[(size_t)dd*NH], acc);
    }
    sacc[tid] = acc;
    __syncthreads();
    if (tid < 32){
      float s = 0.f;
      #pragma unroll
      for (int k=0;k<8;k++) s += sacc[k*32 + tid];
      float invs = 1.f/(sIpart[0]+sIpart[1]);
      float pre = invs*s + b1[(size_t)e*NH + hbase + tid];
      hbuf[(size_t)e*NH + hbase + tid] = 0.5f*pre*(1.f+erff(pre*0.70710678118654752f));
    }
    __syncthreads();
  }
}

// KG: slot_out GEMV. grid 512 = 16e x 32dc. REP x8 diagnostic.
__global__ __launch_bounds__(256) void kg_so(const float* __restrict__ hbuf,
    const float* __restrict__ W2, const float* __restrict__ b2,
    float* __restrict__ slot_out){
  const int e  = blockIdx.x >> 5;
  const int dc = blockIdx.x & 31;
  const int dbase = dc*64;
  const int tid = threadIdx.x;
  __shared__ float hh[1024];
  __shared__ float sacc[256];
  for (int rep=0; rep<REP_BIG; rep++){
    { const float4* h4 = (const float4*)(hbuf + (size_t)e*NH);
      *(float4*)(&hh[tid*4]) = h4[tid]; }
    __syncthreads();
    const int dl = tid&63, hs = tid>>6;
    float acc = 0.f;
    const float* wp = W2 + (size_t)e*NH*DIM + dbase + dl;
    #pragma unroll 16
    for (int h2=0; h2<256; h2++){
      const int hidx = h2*4 + hs;
      acc = fmaf(hh[hidx], wp[(size_t)hidx*DIM], acc);
    }
    sacc[tid] = acc;
    __syncthreads();
    if (tid < 64){
      float s = sacc[tid] + sacc[64+tid] + sacc[128+tid] + sacc[192+tid];
      slot_out[(size_t)e*DIM + dbase + tid] = s + b2[(size_t)e*DIM + dbase + tid];
    }
    __syncthreads();
  }
}

// KH: out = combine @ slot_out. grid 1024. REP x8 diagnostic.
__global__ __launch_bounds__(256) void kh_out(const float* __restrict__ slot_out,
    const float* __restrict__ combine, float* __restrict__ out){
  const int tb = blockIdx.x >> 1;
  const int dc = blockIdx.x & 1;
  const int t0 = tb*16;
  const int d  = dc*1024 + threadIdx.x*4;
  for (int rep=0; rep<REP_BIG; rep++){
    float4 sv[16];
    #pragma unroll
    for (int e=0;e<16;e++) sv[e] = *(const float4*)(slot_out + (size_t)e*DIM + d);
    #pragma unroll 2
    for (int t=0;t<16;t++){
      const float* cr = combine + (size_t)(t0+t)*16;
      float4 a = make_float4(0,0,0,0);
      #pragma unroll
      for (int e=0;e<16;e++){
        float c = cr[e];
        a.x=fmaf(c,sv[e].x,a.x); a.y=fmaf(c,sv[e].y,a.y);
        a.z=fmaf(c,sv[e].z,a.z); a.w=fmaf(c,sv[e].w,a.w);
      }
      *(float4*)(out + (size_t)(t0+t)*DIM + d) = a;
    }
  }
}

extern "C" void kernel_launch(void* const* d_in, const int* in_sizes, int n_in,
                              void* d_out, int out_size, void* d_ws, size_t ws_size,
                              hipStream_t stream) {
  const float* x  = (const float*)d_in[0];
  const float* Wd = (const float*)d_in[1];
  const float* W1 = (const float*)d_in[2];
  const float* b1 = (const float*)d_in[3];
  const float* W2 = (const float*)d_in[4];
  const float* b2 = (const float*)d_in[5];
  float* out = (float*)d_out;
  float* ws  = (float*)d_ws;

  float* part1   = ws + OFF_PART1;
  float* num     = ws + OFF_NUM;
  float* combine = ws + OFF_COMBINE;
  float* csump   = ws + OFF_CSUM;
  float* musump  = ws + OFF_MUSUM;
  float* entp    = ws + OFF_ENT;
  float* part6   = ws + OFF_PART6;
  float* sraw    = ws + OFF_SRAW;
  float* hbuf    = ws + OFF_HBUF;
  float* slot_out= ws + OFF_SLOT;

  ka_logits<<<512, 256, 0, stream>>>(x, Wd, part1);
  kb_router<<<128, 256, 0, stream>>>(part1, num, csump, combine, out + O_GATE,
                                     out + O_TOPI, out + O_TOPW, musump, entp);
  kd_slotin<<<512, 256, 0, stream>>>(x, num, csump, musump, entp, Wd,
                                     part6, out + O_DISP, out + O_LOSS,
                                     out + O_MU, out + O_ENTR);
  ke_sraw<<<256, 256, 0, stream>>>(part6, sraw);
  kf_h<<<512, 256, 0, stream>>>(sraw, W1, b1, csump, hbuf);
  kg_so<<<512, 256, 0, stream>>>(hbuf, W2, b2, slot_out);
  kh_out<<<1024, 256, 0, stream>>>(slot_out, combine, out + O_OUT);
}

// Round 7
// 203.786 us; speedup vs baseline: 5.1923x; 4.3645x over previous
//
#include <hip/hip_runtime.h>
#include <math.h>

#define TTOK 8192
#define DIM  2048
#define NH   1024

// ---- workspace layout (float offsets) ----
// part1 is dead after KB; part6 (same size) aliases it. Total ws = 34.9 MB.
#define OFF_PART1   0u           // [64][8192][16] = 8388608
#define OFF_PART6   0u           // [256][16][2048] = 8388608 (alias of part1)
#define OFF_NUM     8388608u     // [8192][16]
#define OFF_COMBINE 8519680u     // [8192][16]
#define OFF_CSUM    8650752u     // [128][16]
#define OFF_MUSUM   8652800u     // [128][16]
#define OFF_ENT     8654848u     // [128]
#define OFF_SRAW    8654976u     // [16][2048]
#define OFF_HBUF    8687744u     // [16][1024]
#define OFF_SLOT    8704128u     // [16][2048]  -> end 8736896 floats = 34.9 MB

// ---- d_out layout (float offsets) ----
#define O_OUT   0u
#define O_LOSS  16777216u
#define O_GATE  16777217u
#define O_TOPI  16908289u
#define O_TOPW  16924673u
#define O_MU    16941057u
#define O_ENTR  16941073u
#define O_DISP  16941074u

__device__ __forceinline__ float wave_sum(float v){
  #pragma unroll
  for (int o=1;o<64;o<<=1) v += __shfl_xor(v,o,64);
  return v;
}

// KA: logits partials. grid 1024 = 16tb(512tok) x 64kc(32k); 2 tokens/thread.
__global__ __launch_bounds__(256) void ka_logits(const float* __restrict__ x,
                                                 const float* __restrict__ Wd,
                                                 float* __restrict__ part1){
  const int tb = blockIdx.x >> 6;
  const int kc = blockIdx.x & 63;
  const int t0 = tb*512 + threadIdx.x;           // second token: t0+256
  const float4* __restrict__ xr0 = (const float4*)(x + (size_t)t0*DIM + kc*32);
  const float4* __restrict__ xr1 = (const float4*)(x + (size_t)(t0+256)*DIM + kc*32);
  float a0[16], a1[16];
  #pragma unroll
  for (int e=0;e<16;e++){ a0[e]=0.f; a1[e]=0.f; }
  #pragma unroll
  for (int k4=0;k4<8;k4++){
    float4 x0 = xr0[k4];
    float4 x1 = xr1[k4];
    #pragma unroll
    for (int e=0;e<16;e++){
      float4 w = *(const float4*)(Wd + e*DIM + kc*32 + k4*4);
      a0[e] += x0.x*w.x + x0.y*w.y + x0.z*w.z + x0.w*w.w;
      a1[e] += x1.x*w.x + x1.y*w.y + x1.z*w.z + x1.w*w.w;
    }
  }
  float4* p0 = (float4*)(part1 + ((size_t)kc*TTOK + t0)*16);
  p0[0]=make_float4(a0[0],a0[1],a0[2],a0[3]);   p0[1]=make_float4(a0[4],a0[5],a0[6],a0[7]);
  p0[2]=make_float4(a0[8],a0[9],a0[10],a0[11]); p0[3]=make_float4(a0[12],a0[13],a0[14],a0[15]);
  float4* p1 = (float4*)(part1 + ((size_t)kc*TTOK + t0+256)*16);
  p1[0]=make_float4(a1[0],a1[1],a1[2],a1[3]);   p1[1]=make_float4(a1[4],a1[5],a1[6],a1[7]);
  p1[2]=make_float4(a1[8],a1[9],a1[10],a1[11]); p1[3]=make_float4(a1[12],a1[13],a1[14],a1[15]);
}

// KB: reduce part1 (64 kc) -> logits; num=exp; csum partials; row softmax outputs. grid 128
__global__ __launch_bounds__(256) void kb_router(const float* __restrict__ part1,
    float* __restrict__ num, float* __restrict__ csum_part,
    float* __restrict__ combine, float* __restrict__ gate_out,
    float* __restrict__ topi_out, float* __restrict__ topw_out,
    float* __restrict__ musum_part, float* __restrict__ ent_part){
  const int tid = threadIdx.x;
  const int i = blockIdx.x*256 + tid;
  const float4* p1 = (const float4*)part1;
  float4 s = make_float4(0,0,0,0);
  #pragma unroll 8
  for (int kc=0;kc<64;kc++){
    float4 v = p1[(size_t)kc*32768 + i];
    s.x+=v.x; s.y+=v.y; s.z+=v.z; s.w+=v.w;
  }
  float4 n4 = make_float4(expf(s.x),expf(s.y),expf(s.z),expf(s.w));
  ((float4*)num)[i] = n4;
  __shared__ float Lg[64][20];
  const int tl = tid>>2, q = tid&3;
  *(float4*)(&Lg[tl][q*4]) = s;
  float4 n = n4;
  #pragma unroll
  for (int o=4;o<64;o<<=1){
    n.x += __shfl_xor(n.x,o,64); n.y += __shfl_xor(n.y,o,64);
    n.z += __shfl_xor(n.z,o,64); n.w += __shfl_xor(n.w,o,64);
  }
  __shared__ float4 red[4][4];
  const int w = tid>>6, lane = tid&63;
  if (lane<4) red[w][lane] = n;
  __syncthreads();
  if (tid<4){
    float4 a=red[0][tid],b=red[1][tid],c=red[2][tid],d=red[3][tid];
    *(float4*)(csum_part + blockIdx.x*16 + tid*4) =
      make_float4(a.x+b.x+c.x+d.x, a.y+b.y+c.y+d.y, a.z+b.z+c.z+d.z, a.w+b.w+c.w+d.w);
  }
  if (tid < 64){
    const int gt = blockIdx.x*64 + tid;
    float l[16];
    #pragma unroll
    for (int e=0;e<16;e++) l[e] = Lg[tid][e];
    float m = l[0];
    #pragma unroll
    for (int e=1;e<16;e++) m = fmaxf(m,l[e]);
    float c[16]; float sm=0.f;
    #pragma unroll
    for (int e=0;e<16;e++){ c[e]=expf(l[e]-m); sm+=c[e]; }
    float inv = 1.f/sm;
    #pragma unroll
    for (int e=0;e<16;e++) c[e]*=inv;
    float4* co = (float4*)(combine + (size_t)gt*16);
    co[0]=make_float4(c[0],c[1],c[2],c[3]);   co[1]=make_float4(c[4],c[5],c[6],c[7]);
    co[2]=make_float4(c[8],c[9],c[10],c[11]); co[3]=make_float4(c[12],c[13],c[14],c[15]);
    float* go = gate_out + (size_t)gt*16;
    #pragma unroll
    for (int e=0;e<16;e++) go[e]=c[e];
    float v0=-1.f, v1=-1.f; int i0=0, i1=0;
    #pragma unroll
    for (int e=0;e<16;e++){
      float ce=c[e];
      if (ce>v0){ v1=v0; i1=i0; v0=ce; i0=e; }
      else if (ce>v1){ v1=ce; i1=e; }
    }
    float dn = fmaxf(v0+v1, 1e-8f);
    topi_out[(size_t)gt*2+0]=(float)i0; topi_out[(size_t)gt*2+1]=(float)i1;
    topw_out[(size_t)gt*2+0]=v0/dn;     topw_out[(size_t)gt*2+1]=v1/dn;
    float ent=0.f;
    #pragma unroll
    for (int e=0;e<16;e++) ent -= c[e]*logf(c[e]+1e-8f);
    #pragma unroll
    for (int e=0;e<16;e++){
      float v = wave_sum(c[e]);
      if (tid==0) musum_part[blockIdx.x*16+e] = v;
    }
    float ve = wave_sum(ent);
    if (tid==0) ent_part[blockIdx.x] = ve;
  }
}

// KD: slot_in partials + dispatch + block0 finalize. grid 512 = 256tc(32tok) x 2dc
// NOTE: part6 aliases part1 -- safe: KB (which reads part1) completes before KD.
__global__ __launch_bounds__(256) void kd_slotin(const float* __restrict__ x,
    const float* __restrict__ num, const float* __restrict__ csum_part,
    const float* __restrict__ musum_part, const float* __restrict__ ent_part,
    const float* __restrict__ Wd,
    float* __restrict__ part6, float* __restrict__ disp_out,
    float* __restrict__ loss_out, float* __restrict__ mu_out, float* __restrict__ ent_out){
  const int tc = blockIdx.x >> 1;
  const int dc = blockIdx.x & 1;
  const int tid = threadIdx.x;
  const int d  = dc*1024 + tid*4;
  const int t0 = tc*32;
  __shared__ float4 sN[128];
  if (tid < 128) sN[tid] = ((const float4*)num)[t0*4 + tid];
  __syncthreads();
  float4 acc[16];
  #pragma unroll
  for (int e=0;e<16;e++) acc[e]=make_float4(0,0,0,0);
  #pragma unroll 2
  for (int t=0;t<32;t++){
    const float4 xv = *(const float4*)(x + (size_t)(t0+t)*DIM + d);
    #pragma unroll
    for (int qq=0;qq<4;qq++){
      float4 nq = sN[t*4+qq];
      acc[qq*4+0].x=fmaf(nq.x,xv.x,acc[qq*4+0].x); acc[qq*4+0].y=fmaf(nq.x,xv.y,acc[qq*4+0].y);
      acc[qq*4+0].z=fmaf(nq.x,xv.z,acc[qq*4+0].z); acc[qq*4+0].w=fmaf(nq.x,xv.w,acc[qq*4+0].w);
      acc[qq*4+1].x=fmaf(nq.y,xv.x,acc[qq*4+1].x); acc[qq*4+1].y=fmaf(nq.y,xv.y,acc[qq*4+1].y);
      acc[qq*4+1].z=fmaf(nq.y,xv.z,acc[qq*4+1].z); acc[qq*4+1].w=fmaf(nq.y,xv.w,acc[qq*4+1].w);
      acc[qq*4+2].x=fmaf(nq.z,xv.x,acc[qq*4+2].x); acc[qq*4+2].y=fmaf(nq.z,xv.y,acc[qq*4+2].y);
      acc[qq*4+2].z=fmaf(nq.z,xv.z,acc[qq*4+2].z); acc[qq*4+2].w=fmaf(nq.z,xv.w,acc[qq*4+2].w);
      acc[qq*4+3].x=fmaf(nq.w,xv.x,acc[qq*4+3].x); acc[qq*4+3].y=fmaf(nq.w,xv.y,acc[qq*4+3].y);
      acc[qq*4+3].z=fmaf(nq.w,xv.z,acc[qq*4+3].z); acc[qq*4+3].w=fmaf(nq.w,xv.w,acc[qq*4+3].w);
    }
  }
  #pragma unroll
  for (int e=0;e<16;e++)
    *(float4*)(part6 + ((size_t)tc*16+e)*DIM + d) = acc[e];

  if (dc==0){
    __shared__ float sIv[16][16];
    __shared__ float sInv[16];
    { int g = tid>>4, e = tid&15;
      float v=0.f;
      #pragma unroll
      for (int k=0;k<8;k++) v += csum_part[(g*8+k)*16 + e];
      sIv[g][e]=v; }
    __syncthreads();
    if (tid<16){
      float v=0.f;
      #pragma unroll
      for (int g2=0;g2<16;g2++) v+=sIv[g2][tid];
      sInv[tid]=1.f/v;
    }
    __syncthreads();
    const float* sNf = (const float*)sN;
    const int j = tid*2;
    float2 dv = make_float2(sNf[j]*sInv[j&15], sNf[j+1]*sInv[(j+1)&15]);
    *(float2*)(disp_out + (size_t)t0*16 + j) = dv;

    if (tc==0){
      __shared__ float sq[16][16];
      __shared__ float smu[16];
      __shared__ float sqv[16];
      __shared__ float sqe[16];
      {
        int s = tid>>4, ch = tid&15;
        const float* base = Wd + (size_t)s*DIM + ch*128;
        float qv=0.f;
        for (int ii=0;ii<128;ii+=4){ float4 v=*(const float4*)(base+ii); qv+=v.x+v.y+v.z+v.w; }
        sq[s][ch]=qv;
      }
      if (tid<16){
        float mu=0.f;
        for (int b=0;b<128;b++) mu += musum_part[b*16+tid];
        mu/=8192.f;
        mu_out[tid]=mu; smu[tid]=mu;
      }
      if (tid==32){ float es=0.f; for(int b=0;b<128;b++) es+=ent_part[b]; ent_out[0]=es/8192.f; }
      __syncthreads();
      if (tid<16){ float qv=0.f; for(int s=0;s<16;s++) qv+=sq[s][tid]; sqv[tid]=qv/2048.f; }
      __syncthreads();
      if (tid<16){
        float qm=-INFINITY;
        for (int e=0;e<16;e++) qm=fmaxf(qm,sqv[e]);
        sqe[tid]=expf(sqv[tid]-qm);
      }
      __syncthreads();
      if (tid==0){
        float qs=0.f; for(int e=0;e<16;e++) qs+=sqe[e];
        float loss=0.f; for(int e=0;e<16;e++) loss+=smu[e]*(sqe[e]/qs);
        loss_out[0]=16.f*loss;
      }
    }
  }
}

// KE: sraw[i] = sum_tc part6[tc][i]. grid 256 x 256
__global__ __launch_bounds__(256) void ke_sraw(const float* __restrict__ part6,
    float* __restrict__ sraw){
  const int tid = threadIdx.x;
  const int half = tid>>7, il = tid&127;
  const int i = blockIdx.x*128 + il;
  float s=0.f;
  #pragma unroll 8
  for (int tc=half*128; tc<half*128+128; tc++) s += part6[(size_t)tc*32768 + i];
  __shared__ float s2[256];
  s2[tid]=s;
  __syncthreads();
  if (tid<128){
    int ii = blockIdx.x*128 + tid;
    sraw[ii] = s2[tid]+s2[tid+128];
  }
}

// KF: h-GEMV. grid 1024 = 16e x 64hc(16h); 16 waves/CU.
__global__ __launch_bounds__(256) void kf_h(const float* __restrict__ sraw,
    const float* __restrict__ W1, const float* __restrict__ b1,
    const float* __restrict__ csum_part, float* __restrict__ hbuf){
  const int e  = blockIdx.x >> 6;
  const int hc = blockIdx.x & 63;
  const int hbase = hc*16;
  const int tid = threadIdx.x;
  __shared__ float sr[2048];
  __shared__ float sacc[256];
  __shared__ float sIpart[2];
  { const float4* s4 = (const float4*)(sraw + (size_t)e*DIM);
    float4 a = s4[tid*2], b = s4[tid*2+1];
    *(float4*)(&sr[tid*8]) = a; *(float4*)(&sr[tid*8+4]) = b; }
  if (tid < 128){
    float v = csum_part[tid*16 + e];
    #pragma unroll
    for (int o=1;o<64;o<<=1) v += __shfl_xor(v,o,64);
    if ((tid&63)==0) sIpart[tid>>6] = v;
  }
  __syncthreads();
  const int hl = tid&15, ds = tid>>4;            // 16 d-slices of 128
  float acc = 0.f;
  const float* wp = W1 + (size_t)e*DIM*NH + hbase + hl;
  #pragma unroll 16
  for (int i=0;i<128;i++){
    const int dd = ds*128 + i;
    acc = fmaf(sr[dd], wp[(size_t)dd*NH], acc);
  }
  sacc[tid] = acc;
  __syncthreads();
  if (tid < 16){
    float s = 0.f;
    #pragma unroll
    for (int k=0;k<16;k++) s += sacc[k*16 + tid];
    float invs = 1.f/(sIpart[0]+sIpart[1]);
    float pre = invs*s + b1[(size_t)e*NH + hbase + tid];
    hbuf[(size_t)e*NH + hbase + tid] = 0.5f*pre*(1.f+erff(pre*0.70710678118654752f));
  }
}

// KG: slot_out GEMV. grid 1024 = 16e x 64dc(32d); 16 waves/CU.
__global__ __launch_bounds__(256) void kg_so(const float* __restrict__ hbuf,
    const float* __restrict__ W2, const float* __restrict__ b2,
    float* __restrict__ slot_out){
  const int e  = blockIdx.x >> 6;
  const int dc = blockIdx.x & 63;
  const int dbase = dc*32;
  const int tid = threadIdx.x;
  __shared__ float hh[1024];
  __shared__ float sacc[256];
  { const float4* h4 = (const float4*)(hbuf + (size_t)e*NH);
    *(float4*)(&hh[tid*4]) = h4[tid]; }
  __syncthreads();
  const int dl = tid&31, hs = tid>>5;            // 8 h-slices of 128
  float acc = 0.f;
  const float* wp = W2 + (size_t)e*NH*DIM + dbase + dl;
  #pragma unroll 16
  for (int i=0;i<128;i++){
    const int hidx = hs*128 + i;
    acc = fmaf(hh[hidx], wp[(size_t)hidx*DIM], acc);
  }
  sacc[tid] = acc;
  __syncthreads();
  if (tid < 32){
    float s = 0.f;
    #pragma unroll
    for (int k=0;k<8;k++) s += sacc[k*32 + tid];
    slot_out[(size_t)e*DIM + dbase + tid] = s + b2[(size_t)e*DIM + dbase + tid];
  }
}

// KH: out = combine @ slot_out. grid 1024 = 512tb(16tok) x 2dc
__global__ __launch_bounds__(256) void kh_out(const float* __restrict__ slot_out,
    const float* __restrict__ combine, float* __restrict__ out){
  const int tb = blockIdx.x >> 1;
  const int dc = blockIdx.x & 1;
  const int t0 = tb*16;
  const int d  = dc*1024 + threadIdx.x*4;
  float4 sv[16];
  #pragma unroll
  for (int e=0;e<16;e++) sv[e] = *(const float4*)(slot_out + (size_t)e*DIM + d);
  #pragma unroll 2
  for (int t=0;t<16;t++){
    const float* cr = combine + (size_t)(t0+t)*16;
    float4 a = make_float4(0,0,0,0);
    #pragma unroll
    for (int e=0;e<16;e++){
      float c = cr[e];
      a.x=fmaf(c,sv[e].x,a.x); a.y=fmaf(c,sv[e].y,a.y);
      a.z=fmaf(c,sv[e].z,a.z); a.w=fmaf(c,sv[e].w,a.w);
    }
    *(float4*)(out + (size_t)(t0+t)*DIM + d) = a;
  }
}

extern "C" void kernel_launch(void* const* d_in, const int* in_sizes, int n_in,
                              void* d_out, int out_size, void* d_ws, size_t ws_size,
                              hipStream_t stream) {
  const float* x  = (const float*)d_in[0];
  const float* Wd = (const float*)d_in[1];
  const float* W1 = (const float*)d_in[2];
  const float* b1 = (const float*)d_in[3];
  const float* W2 = (const float*)d_in[4];
  const float* b2 = (const float*)d_in[5];
  float* out = (float*)d_out;
  float* ws  = (float*)d_ws;

  float* part1   = ws + OFF_PART1;
  float* num     = ws + OFF_NUM;
  float* combine = ws + OFF_COMBINE;
  float* csump   = ws + OFF_CSUM;
  float* musump  = ws + OFF_MUSUM;
  float* entp    = ws + OFF_ENT;
  float* part6   = ws + OFF_PART6;   // alias of part1 (part1 dead after KB)
  float* sraw    = ws + OFF_SRAW;
  float* hbuf    = ws + OFF_HBUF;
  float* slot_out= ws + OFF_SLOT;

  ka_logits<<<1024, 256, 0, stream>>>(x, Wd, part1);
  kb_router<<<128, 256, 0, stream>>>(part1, num, csump, combine, out + O_GATE,
                                     out + O_TOPI, out + O_TOPW, musump, entp);
  kd_slotin<<<512, 256, 0, stream>>>(x, num, csump, musump, entp, Wd,
                                     part6, out + O_DISP, out + O_LOSS,
                                     out + O_MU, out + O_ENTR);
  ke_sraw<<<256, 256, 0, stream>>>(part6, sraw);
  kf_h<<<1024, 256, 0, stream>>>(sraw, W1, b1, csump, hbuf);
  kg_so<<<1024, 256, 0, stream>>>(hbuf, W2, b2, slot_out);
  kh_out<<<1024, 256, 0, stream>>>(slot_out, combine, out + O_OUT);
}